// Round 2
// baseline (597.957 us; speedup 1.0000x reference)
//
#include <hip/hip_runtime.h>
#include <cstdint>
#include <cstddef>

#define IN_F 768
#define HID  64
#define NNZ1 4915
#define NNZ2 409
#define NNZ3 32
#define BATCH 131072

// ---- workspace layout (bytes) ----
#define OFF_W1D 0u
#define OFF_W2D 196608u          // 768*64*4
#define OFF_W3D 212992u          // +64*64*4
#define OFF_W1F 213248u          // +256 (W3 padded)
#define OFF_W2F 311552u          // +24*4*64*16
#define WS_NEED 319744u

typedef __bf16 bf16x8 __attribute__((ext_vector_type(8)));
typedef float  f32x4  __attribute__((ext_vector_type(4)));
typedef float  f32x8  __attribute__((ext_vector_type(8)));

union FragU { bf16x8 v; uint32_t u[4]; uint4 q; };
union F8U   { float4 f4[2]; f32x8 v8; };

__device__ __forceinline__ uint32_t f2bf1(float f) {
    uint32_t u = __float_as_uint(f);
    return (u + 0x7FFFu + ((u >> 16) & 1u)) >> 16;   // RNE
}
__device__ __forceinline__ uint32_t f2bf2(float lo, float hi) {
    uint32_t a = __float_as_uint(lo);
    uint32_t b = __float_as_uint(hi);
    a = a + 0x7FFFu + ((a >> 16) & 1u);
    b = b + 0x7FFFu + ((b >> 16) & 1u);
    return (a >> 16) | (b & 0xFFFF0000u);
}

// pack 8 fp32 -> bf16x8 via hardware v_cvt_pk_bf16_f32 (RNE on gfx950)
__device__ __forceinline__ bf16x8 pack8(float4 a, float4 b) {
    F8U u; u.f4[0] = a; u.f4[1] = b;
    return __builtin_convertvector(u.v8, bf16x8);
}

// ---- COO -> dense scatter (duplicates accumulate) ----
__global__ void scatter_coo(const int* __restrict__ idx1, const float* __restrict__ val1,
                            const int* __restrict__ idx2, const float* __restrict__ val2,
                            const int* __restrict__ idx3, const float* __restrict__ val3,
                            float* __restrict__ W1d, float* __restrict__ W2d,
                            float* __restrict__ W3d) {
    int t = blockIdx.x * blockDim.x + threadIdx.x;
    if (t < NNZ1) {
        int r = idx1[t], c = idx1[NNZ1 + t];
        atomicAdd(&W1d[r * HID + c], val1[t]);
    } else if (t < NNZ1 + NNZ2) {
        int i = t - NNZ1;
        int r = idx2[i], c = idx2[NNZ2 + i];
        atomicAdd(&W2d[r * HID + c], val2[i]);
    } else if (t < NNZ1 + NNZ2 + NNZ3) {
        int i = t - NNZ1 - NNZ2;
        int r = idx3[i], c = idx3[NNZ3 + i];
        atomicAdd(&W3d[r * 1 + c], val3[i]);   // OUT==1 -> c==0
    }
}

// ---- dense fp32 -> bf16 MFMA B-fragment layout ----
// B operand of mfma_f32_16x16x32_bf16: lane holds B[k=(lane>>4)*8+j][n=lane&15].
__global__ void frag_build(const float* __restrict__ W1d, const float* __restrict__ W2d,
                           uint4* __restrict__ W1f, uint4* __restrict__ W2f) {
    int t = blockIdx.x * blockDim.x + threadIdx.x;
    const int n1 = 24 * 4 * 64;
    const int n2 = 2 * 4 * 64;
    if (t < n1) {
        int lane = t & 63;
        int fi = t >> 6;
        int kstep = fi >> 2, nt = fi & 3;
        int m = lane & 15, quad = lane >> 4;
        uint32_t u[4];
#pragma unroll
        for (int jj = 0; jj < 4; ++jj) {
            int k = kstep * 32 + quad * 8 + jj * 2;
            u[jj] = f2bf2(W1d[k * HID + nt * 16 + m], W1d[(k + 1) * HID + nt * 16 + m]);
        }
        W1f[t] = make_uint4(u[0], u[1], u[2], u[3]);
    } else if (t < n1 + n2) {
        int tt = t - n1;
        int lane = tt & 63;
        int fi = tt >> 6;
        int kstep = fi >> 2, nt = fi & 3;
        int m = lane & 15, quad = lane >> 4;
        uint32_t u[4];
#pragma unroll
        for (int jj = 0; jj < 4; ++jj) {
            int k = kstep * 32 + quad * 8 + jj * 2;
            u[jj] = f2bf2(W2d[k * HID + nt * 16 + m], W2d[(k + 1) * HID + nt * 16 + m]);
        }
        W2f[tt] = make_uint4(u[0], u[1], u[2], u[3]);
    }
}

// ---- fused 3-layer MLP ----
// Block = 256 threads = 4 waves; each wave computes 32 batch rows (2 M-tiles
// sharing B-frags). Grid = 1024 blocks -> 4096 waves = exactly 4 waves/SIMD
// full residency at <=128 VGPR. Depth-2 software prefetch of x + W1f.
__global__ __launch_bounds__(256, 4) void mlp_fused(
    const float* __restrict__ x,
    const uint4* __restrict__ W1f,
    const uint4* __restrict__ W2f,
    const float* __restrict__ W3d,
    const float* __restrict__ b1,
    const float* __restrict__ b2,
    const float* __restrict__ b3,
    float* __restrict__ out)
{
    // row stride 72 u16 = 144 B: 16B-aligned for ds_read_b128, breaks pow2 banks
    __shared__ __align__(16) uint16_t h1s[4][32][72];

    const int lane = threadIdx.x & 63;
    const int w    = threadIdx.x >> 6;
    const int m    = lane & 15;
    const int quad = lane >> 4;
    const int rowbase = blockIdx.x * 128 + w * 32;

    f32x4 acc0[4] = {{0,0,0,0},{0,0,0,0},{0,0,0,0},{0,0,0,0}};
    f32x4 acc1[4] = {{0,0,0,0},{0,0,0,0},{0,0,0,0},{0,0,0,0}};

    // A operand: lane holds A[m=lane&15][k=quad*8+j], j=0..7 contiguous
    const float* xr0 = x + (size_t)(rowbase + m) * IN_F + quad * 8;
    const float* xr1 = xr0 + (size_t)16 * IN_F;
    const uint4* w1p = W1f + lane;

    float4 xa[2][4];   // [buf][t0a,t0b,t1a,t1b]
    uint4  bq[2][4];   // [buf][nt]

    // prologue: load k=0 -> buf0, k=1 -> buf1
#pragma unroll
    for (int kk = 0; kk < 2; ++kk) {
        xa[kk][0] = *(const float4*)(xr0 + kk * 32);
        xa[kk][1] = *(const float4*)(xr0 + kk * 32 + 4);
        xa[kk][2] = *(const float4*)(xr1 + kk * 32);
        xa[kk][3] = *(const float4*)(xr1 + kk * 32 + 4);
#pragma unroll
        for (int nt = 0; nt < 4; ++nt) bq[kk][nt] = w1p[(kk * 4 + nt) * 64];
    }

#pragma unroll 2
    for (int k = 0; k < 24; ++k) {
        const int cb = k & 1;
        // consume point: wait for k's data (issued 2 iters ago)
        const float4 x0a = xa[cb][0], x0b = xa[cb][1];
        const float4 x1a = xa[cb][2], x1b = xa[cb][3];
        FragU b0, b1f, b2f, b3f;
        b0.q = bq[cb][0]; b1f.q = bq[cb][1]; b2f.q = bq[cb][2]; b3f.q = bq[cb][3];
        // prefetch k+2 into the slot just consumed
        if (k < 22) {
            const int kn = k + 2;
            xa[cb][0] = *(const float4*)(xr0 + kn * 32);
            xa[cb][1] = *(const float4*)(xr0 + kn * 32 + 4);
            xa[cb][2] = *(const float4*)(xr1 + kn * 32);
            xa[cb][3] = *(const float4*)(xr1 + kn * 32 + 4);
#pragma unroll
            for (int nt = 0; nt < 4; ++nt) bq[cb][nt] = w1p[(kn * 4 + nt) * 64];
        }
        FragU a0, a1;
        a0.v = pack8(x0a, x0b);
        a1.v = pack8(x1a, x1b);
        acc0[0] = __builtin_amdgcn_mfma_f32_16x16x32_bf16(a0.v, b0.v,  acc0[0], 0, 0, 0);
        acc0[1] = __builtin_amdgcn_mfma_f32_16x16x32_bf16(a0.v, b1f.v, acc0[1], 0, 0, 0);
        acc0[2] = __builtin_amdgcn_mfma_f32_16x16x32_bf16(a0.v, b2f.v, acc0[2], 0, 0, 0);
        acc0[3] = __builtin_amdgcn_mfma_f32_16x16x32_bf16(a0.v, b3f.v, acc0[3], 0, 0, 0);
        acc1[0] = __builtin_amdgcn_mfma_f32_16x16x32_bf16(a1.v, b0.v,  acc1[0], 0, 0, 0);
        acc1[1] = __builtin_amdgcn_mfma_f32_16x16x32_bf16(a1.v, b1f.v, acc1[1], 0, 0, 0);
        acc1[2] = __builtin_amdgcn_mfma_f32_16x16x32_bf16(a1.v, b2f.v, acc1[2], 0, 0, 0);
        acc1[3] = __builtin_amdgcn_mfma_f32_16x16x32_bf16(a1.v, b3f.v, acc1[3], 0, 0, 0);
    }

    // Epilogue 1: h1 = relu(acc + b1) -> LDS as bf16.
    // C layout: col = lane&15 (+16*nt), row = quad*4 + reg (+16*Mtile).
#pragma unroll
    for (int nt = 0; nt < 4; ++nt) {
        const int col = nt * 16 + m;
        const float bias = b1[col];
#pragma unroll
        for (int r = 0; r < 4; ++r) {
            float h0 = acc0[nt][r] + bias;
            h0 = h0 > 0.f ? h0 : 0.f;
            h1s[w][quad * 4 + r][col] = (uint16_t)f2bf1(h0);
            float h1 = acc1[nt][r] + bias;
            h1 = h1 > 0.f ? h1 : 0.f;
            h1s[w][16 + quad * 4 + r][col] = (uint16_t)f2bf1(h1);
        }
    }
    // Same-wave RAW only (each wave reads its own h1s[w]); compiler inserts wait.

    // Layer 2: 2 K-steps x 4 N-tiles x 2 M-tiles
    f32x4 acc20[4] = {{0,0,0,0},{0,0,0,0},{0,0,0,0},{0,0,0,0}};
    f32x4 acc21[4] = {{0,0,0,0},{0,0,0,0},{0,0,0,0},{0,0,0,0}};
#pragma unroll
    for (int k2 = 0; k2 < 2; ++k2) {
        FragU a20, a21;
        a20.q = *(const uint4*)&h1s[w][m][k2 * 32 + quad * 8];
        a21.q = *(const uint4*)&h1s[w][16 + m][k2 * 32 + quad * 8];
#pragma unroll
        for (int nt = 0; nt < 4; ++nt) {
            FragU bb; bb.q = W2f[(k2 * 4 + nt) * 64 + lane];
            acc20[nt] = __builtin_amdgcn_mfma_f32_16x16x32_bf16(a20.v, bb.v, acc20[nt], 0, 0, 0);
            acc21[nt] = __builtin_amdgcn_mfma_f32_16x16x32_bf16(a21.v, bb.v, acc21[nt], 0, 0, 0);
        }
    }

    // Epilogue 2 + Layer 3 (fp32)
    float w3v[4];
#pragma unroll
    for (int nt = 0; nt < 4; ++nt) w3v[nt] = W3d[nt * 16 + m];

    float p0[4] = {0.f, 0.f, 0.f, 0.f};
    float p1[4] = {0.f, 0.f, 0.f, 0.f};
#pragma unroll
    for (int nt = 0; nt < 4; ++nt) {
        const float bias = b2[nt * 16 + m];
#pragma unroll
        for (int r = 0; r < 4; ++r) {
            float h0 = acc20[nt][r] + bias;
            h0 = h0 > 0.f ? h0 : 0.f;
            p0[r] += h0 * w3v[nt];
            float h1 = acc21[nt][r] + bias;
            h1 = h1 > 0.f ? h1 : 0.f;
            p1[r] += h1 * w3v[nt];
        }
    }
#pragma unroll
    for (int off = 1; off < 16; off <<= 1) {
#pragma unroll
        for (int r = 0; r < 4; ++r) {
            p0[r] += __shfl_xor(p0[r], off, 16);
            p1[r] += __shfl_xor(p1[r], off, 16);
        }
    }
    const float bb3 = b3[0];
    if (m == 0) {
#pragma unroll
        for (int r = 0; r < 4; ++r) {
            out[rowbase + quad * 4 + r] = p0[r] + bb3;
            out[rowbase + 16 + quad * 4 + r] = p1[r] + bb3;
        }
    }
}

extern "C" void kernel_launch(void* const* d_in, const int* in_sizes, int n_in,
                              void* d_out, int out_size, void* d_ws, size_t ws_size,
                              hipStream_t stream) {
    const float* x    = (const float*)d_in[0];
    const int*   idx1 = (const int*)  d_in[1];
    const float* val1 = (const float*)d_in[2];
    const float* b1   = (const float*)d_in[3];
    const int*   idx2 = (const int*)  d_in[4];
    const float* val2 = (const float*)d_in[5];
    const float* b2   = (const float*)d_in[6];
    const int*   idx3 = (const int*)  d_in[7];
    const float* val3 = (const float*)d_in[8];
    const float* b3   = (const float*)d_in[9];
    float* out = (float*)d_out;

    char* ws = (char*)d_ws;
    float* W1d = (float*)(ws + OFF_W1D);
    float* W2d = (float*)(ws + OFF_W2D);
    float* W3d = (float*)(ws + OFF_W3D);
    uint4* W1f = (uint4*)(ws + OFF_W1F);
    uint4* W2f = (uint4*)(ws + OFF_W2F);

    // zero the dense weight buffers (ws is poisoned 0xAA before every launch)
    hipMemsetAsync(d_ws, 0, OFF_W1F, stream);

    const int nnz_total = NNZ1 + NNZ2 + NNZ3;
    scatter_coo<<<(nnz_total + 255) / 256, 256, 0, stream>>>(
        idx1, val1, idx2, val2, idx3, val3, W1d, W2d, W3d);

    const int nfrag = 24 * 4 * 64 + 2 * 4 * 64;
    frag_build<<<(nfrag + 255) / 256, 256, 0, stream>>>(W1d, W2d, W1f, W2f);

    mlp_fused<<<BATCH / 128, 256, 0, stream>>>(x, W1f, W2f, W3d, b1, b2, b3, out);
}

// Round 3
// 555.813 us; speedup vs baseline: 1.0758x; 1.0758x over previous
//
#include <hip/hip_runtime.h>
#include <cstdint>
#include <cstddef>

#define IN_F 768
#define HID  64
#define NNZ1 4915
#define NNZ2 409
#define NNZ3 32
#define BATCH 131072

// ---- workspace layout (bytes) ----
#define OFF_W1D 0u
#define OFF_W2D 196608u          // 768*64*4
#define OFF_W3D 212992u          // +64*64*4
#define OFF_W1F 213248u          // +256 (W3 padded)
#define OFF_W2F 311552u          // +24*4*64*16
#define WS_NEED 319744u

typedef __bf16 bf16x8 __attribute__((ext_vector_type(8)));
typedef float  f32x4  __attribute__((ext_vector_type(4)));
typedef float  f32x8  __attribute__((ext_vector_type(8)));

union FragU { bf16x8 v; uint32_t u[4]; uint4 q; };
union F8U   { float4 f4[2]; f32x8 v8; };

__device__ __forceinline__ uint32_t f2bf1(float f) {
    uint32_t u = __float_as_uint(f);
    return (u + 0x7FFFu + ((u >> 16) & 1u)) >> 16;   // RNE
}
__device__ __forceinline__ uint32_t f2bf2(float lo, float hi) {
    uint32_t a = __float_as_uint(lo);
    uint32_t b = __float_as_uint(hi);
    a = a + 0x7FFFu + ((a >> 16) & 1u);
    b = b + 0x7FFFu + ((b >> 16) & 1u);
    return (a >> 16) | (b & 0xFFFF0000u);
}

// pack 8 fp32 -> bf16x8 via hardware v_cvt_pk_bf16_f32 (RNE, verified R2: absmax identical)
__device__ __forceinline__ bf16x8 pack8(float4 a, float4 b) {
    F8U u; u.f4[0] = a; u.f4[1] = b;
    return __builtin_convertvector(u.v8, bf16x8);
}

// ---- COO -> dense scatter (duplicates accumulate) ----
__global__ void scatter_coo(const int* __restrict__ idx1, const float* __restrict__ val1,
                            const int* __restrict__ idx2, const float* __restrict__ val2,
                            const int* __restrict__ idx3, const float* __restrict__ val3,
                            float* __restrict__ W1d, float* __restrict__ W2d,
                            float* __restrict__ W3d) {
    int t = blockIdx.x * blockDim.x + threadIdx.x;
    if (t < NNZ1) {
        int r = idx1[t], c = idx1[NNZ1 + t];
        atomicAdd(&W1d[r * HID + c], val1[t]);
    } else if (t < NNZ1 + NNZ2) {
        int i = t - NNZ1;
        int r = idx2[i], c = idx2[NNZ2 + i];
        atomicAdd(&W2d[r * HID + c], val2[i]);
    } else if (t < NNZ1 + NNZ2 + NNZ3) {
        int i = t - NNZ1 - NNZ2;
        int r = idx3[i], c = idx3[NNZ3 + i];
        atomicAdd(&W3d[r * 1 + c], val3[i]);   // OUT==1 -> c==0
    }
}

// ---- dense fp32 -> bf16 MFMA B-fragment layout ----
// W1f uses a PERMUTED k-axis so the mlp kernel's x loads are 64B/lane
// (256B/row) contiguous: within 64-col window w (kstep = 2w+s, s in {0,1}),
//   global_k(quad, j) = 64*w + quad*16 + s*8 + j
// A-side uses the same permutation (lane's 64B slice split into two frags).
// W2f keeps the STANDARD mapping (layer-2 A comes from LDS in standard order):
//   global_k = kstep*32 + quad*8 + j
__global__ void frag_build(const float* __restrict__ W1d, const float* __restrict__ W2d,
                           uint4* __restrict__ W1f, uint4* __restrict__ W2f) {
    int t = blockIdx.x * blockDim.x + threadIdx.x;
    const int n1 = 24 * 4 * 64;
    const int n2 = 2 * 4 * 64;
    if (t < n1) {
        int lane = t & 63;
        int fi = t >> 6;
        int kstep = fi >> 2, nt = fi & 3;
        int m = lane & 15, quad = lane >> 4;
        int kbase = (kstep >> 1) * 64 + quad * 16 + (kstep & 1) * 8;   // permuted
        uint32_t u[4];
#pragma unroll
        for (int jj = 0; jj < 4; ++jj) {
            int k = kbase + jj * 2;
            u[jj] = f2bf2(W1d[k * HID + nt * 16 + m], W1d[(k + 1) * HID + nt * 16 + m]);
        }
        W1f[t] = make_uint4(u[0], u[1], u[2], u[3]);
    } else if (t < n1 + n2) {
        int tt = t - n1;
        int lane = tt & 63;
        int fi = tt >> 6;
        int kstep = fi >> 2, nt = fi & 3;
        int m = lane & 15, quad = lane >> 4;
        uint32_t u[4];
#pragma unroll
        for (int jj = 0; jj < 4; ++jj) {
            int k = kstep * 32 + quad * 8 + jj * 2;                    // standard
            u[jj] = f2bf2(W2d[k * HID + nt * 16 + m], W2d[(k + 1) * HID + nt * 16 + m]);
        }
        W2f[tt] = make_uint4(u[0], u[1], u[2], u[3]);
    }
}

// ---- fused 3-layer MLP ----
// Block = 256 threads = 4 waves; each wave computes 16 batch rows (round-1
// structure — R2's 32-row+prefetch variant spilled and regressed).
// Layer 1: 12 windows x 64 cols; lane loads 64B contiguous of its row
// (k-permuted frags), x double-buffered across windows. 8 MFMA/window.
__global__ __launch_bounds__(256) void mlp_fused(
    const float* __restrict__ x,
    const uint4* __restrict__ W1f,
    const uint4* __restrict__ W2f,
    const float* __restrict__ W3d,
    const float* __restrict__ b1,
    const float* __restrict__ b2,
    const float* __restrict__ b3,
    float* __restrict__ out)
{
    __shared__ __align__(16) uint16_t h1s[4][16][72];  // stride 72 u16 = 144B

    const int lane = threadIdx.x & 63;
    const int w    = threadIdx.x >> 6;
    const int m    = lane & 15;
    const int quad = lane >> 4;
    const int rowbase = blockIdx.x * 64 + w * 16;

    f32x4 acc[4] = {{0,0,0,0},{0,0,0,0},{0,0,0,0},{0,0,0,0}};

    // lane's slice of its row: 64B window base = col 64*win + quad*16
    const float* xr = x + (size_t)(rowbase + m) * IN_F + quad * 16;
    const uint4* w1p = W1f + lane;

    float4 xw[2][4];
#pragma unroll
    for (int i = 0; i < 4; ++i) {
        xw[0][i] = *(const float4*)(xr + 0 * 64 + i * 4);
        xw[1][i] = *(const float4*)(xr + 1 * 64 + i * 4);
    }

#pragma unroll 2
    for (int win = 0; win < 12; ++win) {
        const int cb = win & 1;
        const float4 x0 = xw[cb][0], x1 = xw[cb][1], x2 = xw[cb][2], x3 = xw[cb][3];
        if (win < 10) {
#pragma unroll
            for (int i = 0; i < 4; ++i)
                xw[cb][i] = *(const float4*)(xr + (win + 2) * 64 + i * 4);
        }
        // B frags for this window: 2 ksteps x 4 ntiles, index = win*8 + s*4 + nt
        uint4 bq[8];
#pragma unroll
        for (int i = 0; i < 8; ++i) bq[i] = w1p[(win * 8 + i) * 64];

        FragU a0, a1;
        a0.v = pack8(x0, x1);   // s=0: floats 0..7  -> global_k = 64*win + quad*16 + j
        a1.v = pack8(x2, x3);   // s=1: floats 8..15 -> global_k = ... + 8 + j
#pragma unroll
        for (int nt = 0; nt < 4; ++nt) {
            FragU bb; bb.q = bq[nt];
            acc[nt] = __builtin_amdgcn_mfma_f32_16x16x32_bf16(a0.v, bb.v, acc[nt], 0, 0, 0);
        }
#pragma unroll
        for (int nt = 0; nt < 4; ++nt) {
            FragU bb; bb.q = bq[4 + nt];
            acc[nt] = __builtin_amdgcn_mfma_f32_16x16x32_bf16(a1.v, bb.v, acc[nt], 0, 0, 0);
        }
    }

    // Epilogue 1: h1 = relu(acc + b1) -> LDS as bf16.
    // C layout: col = lane&15 (+16*nt), row = quad*4 + reg.
#pragma unroll
    for (int nt = 0; nt < 4; ++nt) {
        const int col = nt * 16 + m;
        const float bias = b1[col];
#pragma unroll
        for (int r = 0; r < 4; ++r) {
            float h = acc[nt][r] + bias;
            h = h > 0.f ? h : 0.f;
            h1s[w][quad * 4 + r][col] = (uint16_t)f2bf1(h);
        }
    }
    // Same-wave RAW only (each wave reads its own h1s[w]); compiler inserts wait.

    // Layer 2: 2 K-steps x 4 N-tiles (standard frag mapping)
    f32x4 acc2[4] = {{0,0,0,0},{0,0,0,0},{0,0,0,0},{0,0,0,0}};
#pragma unroll
    for (int k2 = 0; k2 < 2; ++k2) {
        FragU a2;
        a2.q = *(const uint4*)&h1s[w][m][k2 * 32 + quad * 8];
#pragma unroll
        for (int nt = 0; nt < 4; ++nt) {
            FragU bb; bb.q = W2f[(k2 * 4 + nt) * 64 + lane];
            acc2[nt] = __builtin_amdgcn_mfma_f32_16x16x32_bf16(a2.v, bb.v, acc2[nt], 0, 0, 0);
        }
    }

    // Epilogue 2 + Layer 3 (fp32)
    float w3v[4];
#pragma unroll
    for (int nt = 0; nt < 4; ++nt) w3v[nt] = W3d[nt * 16 + m];

    float p[4] = {0.f, 0.f, 0.f, 0.f};
#pragma unroll
    for (int nt = 0; nt < 4; ++nt) {
        const float bias = b2[nt * 16 + m];
#pragma unroll
        for (int r = 0; r < 4; ++r) {
            float h = acc2[nt][r] + bias;
            h = h > 0.f ? h : 0.f;
            p[r] += h * w3v[nt];
        }
    }
#pragma unroll
    for (int off = 1; off < 16; off <<= 1) {
#pragma unroll
        for (int r = 0; r < 4; ++r) p[r] += __shfl_xor(p[r], off, 16);
    }
    const float bb3 = b3[0];
    if (m == 0) {
#pragma unroll
        for (int r = 0; r < 4; ++r) out[rowbase + quad * 4 + r] = p[r] + bb3;
    }
}

extern "C" void kernel_launch(void* const* d_in, const int* in_sizes, int n_in,
                              void* d_out, int out_size, void* d_ws, size_t ws_size,
                              hipStream_t stream) {
    const float* x    = (const float*)d_in[0];
    const int*   idx1 = (const int*)  d_in[1];
    const float* val1 = (const float*)d_in[2];
    const float* b1   = (const float*)d_in[3];
    const int*   idx2 = (const int*)  d_in[4];
    const float* val2 = (const float*)d_in[5];
    const float* b2   = (const float*)d_in[6];
    const int*   idx3 = (const int*)  d_in[7];
    const float* val3 = (const float*)d_in[8];
    const float* b3   = (const float*)d_in[9];
    float* out = (float*)d_out;

    char* ws = (char*)d_ws;
    float* W1d = (float*)(ws + OFF_W1D);
    float* W2d = (float*)(ws + OFF_W2D);
    float* W3d = (float*)(ws + OFF_W3D);
    uint4* W1f = (uint4*)(ws + OFF_W1F);
    uint4* W2f = (uint4*)(ws + OFF_W2F);

    // zero the dense weight buffers (ws is poisoned 0xAA before every launch)
    hipMemsetAsync(d_ws, 0, OFF_W1F, stream);

    const int nnz_total = NNZ1 + NNZ2 + NNZ3;
    scatter_coo<<<(nnz_total + 255) / 256, 256, 0, stream>>>(
        idx1, val1, idx2, val2, idx3, val3, W1d, W2d, W3d);

    const int nfrag = 24 * 4 * 64 + 2 * 4 * 64;
    frag_build<<<(nfrag + 255) / 256, 256, 0, stream>>>(W1d, W2d, W1f, W2f);

    mlp_fused<<<BATCH / 64, 256, 0, stream>>>(x, W1f, W2f, W3d, b1, b2, b3, out);
}